// Round 5
// baseline (77.908 us; speedup 1.0000x reference)
//
#include <hip/hip_runtime.h>

// Problem: B=8, N=2048, K=32, C=256, COND=512 — ALL FLOAT32 I/O, coords int32.
//  0 node_feats [8,2048,256] f32
//  1 cond_feats [8,512] f32
//  2 W_cond     [512,512] f32
//  3 b_cond     [512] f32
//  4 W_film     [256,256] f32
//  5 b_film     [256] f32
//  6 weights    [8,65536,1] f32
//  7 params     [8,65536,1] f32
//  8 coords     [524288] int32 in [0,16384)
// Output: f32 [8,2048,256]

typedef unsigned short u16;
typedef unsigned int u32;

typedef __attribute__((ext_vector_type(8))) __bf16 bf16x8;
typedef __attribute__((ext_vector_type(8))) u16 u16x8;
typedef __attribute__((ext_vector_type(4))) float f32x4;
typedef __attribute__((ext_vector_type(4))) u16 u16x4;

__device__ __forceinline__ float b2f(u16 u) {
  union { u32 i; float f; } x; x.i = ((u32)u) << 16; return x.f;
}
__device__ __forceinline__ u16 f2b(float f) {
  union { float f; u32 i; } x; x.f = f;
  u32 r = (x.i + 0x7fffu + ((x.i >> 16) & 1u)) >> 16;
  return (u16)r;
}

// ---------------------------------------------------------------------------
// K0: prep. Blocks 0..31: W_film repack to MFMA-B fragment order (bf16).
//     Blocks 32..47: cond GEMM gamma/beta (each block: one batch half, 256 cols).
// Wp[((ct*8+ks)*64+l)*8+j] = bf16(Wf[(ks*32+(l>>4)*8+j)*256 + ct*16+(l&15)])
// gb[b][0:256]=gamma(+1), gb[b][256:512]=beta
// ---------------------------------------------------------------------------
__global__ __launch_bounds__(256) void k_prep(const float* __restrict__ Wf,
                                              u16* __restrict__ Wp,
                                              const float* __restrict__ cond,
                                              const float* __restrict__ Wc,
                                              const float* __restrict__ bc,
                                              float* __restrict__ gb) {
  if (blockIdx.x < 32) {
    int i0 = blockIdx.x * 2048 + threadIdx.x;
    #pragma unroll
    for (int u = 0; u < 8; ++u) {
      int i = i0 + u * 256;
      int j  = i & 7;
      int l  = (i >> 3) & 63;
      int ks = (i >> 9) & 7;
      int ct = i >> 12;
      int k   = ks * 32 + ((l >> 4) << 3) + j;
      int col = ct * 16 + (l & 15);
      Wp[i] = f2b(Wf[k * 256 + col]);
    }
  } else {
    int b  = (blockIdx.x - 32) >> 1;
    int jj = ((blockIdx.x - 32) & 1) * 256 + threadIdx.x;
    __shared__ float cf[512];
    cf[threadIdx.x]       = cond[b * 512 + threadIdx.x];
    cf[threadIdx.x + 256] = cond[b * 512 + 256 + threadIdx.x];
    __syncthreads();
    float a = bc[jj];
    #pragma unroll 8
    for (int i = 0; i < 512; ++i)
      a += cf[i] * Wc[i * 512 + jj];
    if (jj < 256) a += 1.0f;   // gamma
    gb[b * 512 + jj] = a;
  }
}

// ---------------------------------------------------------------------------
// K2: nnf = bf16( relu(LN(node_feats @ W_film + b_film) * gamma + beta) )
// Block = 256 thr = 4 waves, 16 rows. A-fragments direct from global
// (4 waves share the same 128B lines -> L1 merge), f32 -> bf16 on the fly.
// Wave w computes col-tiles ct = w*4..w*4+3. LN stats: intra-wave shfl over
// 16-lane groups, cross-wave via small LDS buffer.
// D frag: col = ct*16+(l&15), row = row0 + (l>>4)*4 + r   [m89-verified]
// ---------------------------------------------------------------------------
__global__ __launch_bounds__(256) void k_film(const float* __restrict__ A,
                                              const u16* __restrict__ Wp,
                                              const float* __restrict__ bfm,
                                              const float* __restrict__ gb,
                                              u16* __restrict__ nnf) {
  const int tid = threadIdx.x;
  const int l = tid & 63;
  const int w = tid >> 6;             // wave 0..3
  const int row0 = blockIdx.x * 16;   // 1024 blocks
  const int b = row0 >> 11;

  __shared__ float red[4][4][2][4];   // [wave][group][s|q][r]

  f32x4 acc[4];
  #pragma unroll
  for (int c = 0; c < 4; ++c) {
    acc[c].x = 0.f; acc[c].y = 0.f; acc[c].z = 0.f; acc[c].w = 0.f;
  }

  // A frag: lane l -> row (l&15), k = ks*32 + (l>>4)*8 + j
  const float* arow = A + (size_t)(row0 + (l & 15)) * 256 + ((l >> 4) << 3);
  const u16* wl = Wp + (size_t)l * 8;

  #pragma unroll
  for (int ks = 0; ks < 8; ++ks) {
    f32x4 a0 = __builtin_nontemporal_load((const f32x4*)(arow + ks * 32));
    f32x4 a1 = __builtin_nontemporal_load((const f32x4*)(arow + ks * 32 + 4));
    bf16x8 af;
    af[0] = (__bf16)a0.x; af[1] = (__bf16)a0.y;
    af[2] = (__bf16)a0.z; af[3] = (__bf16)a0.w;
    af[4] = (__bf16)a1.x; af[5] = (__bf16)a1.y;
    af[6] = (__bf16)a1.z; af[7] = (__bf16)a1.w;
    #pragma unroll
    for (int c = 0; c < 4; ++c) {
      int ct = w * 4 + c;
      bf16x8 bfr = *(const bf16x8*)(wl + ((size_t)(ct * 8 + ks)) * 512);
      acc[c] = __builtin_amdgcn_mfma_f32_16x16x32_bf16(af, bfr, acc[c], 0, 0, 0);
    }
  }

  // bias + partial row sums/sumsq over this wave's 64 cols
  float s[4] = {0.f, 0.f, 0.f, 0.f};
  float q[4] = {0.f, 0.f, 0.f, 0.f};
  #pragma unroll
  for (int c = 0; c < 4; ++c) {
    float bcol = bfm[(w * 4 + c) * 16 + (l & 15)];
    #pragma unroll
    for (int r = 0; r < 4; ++r) {
      float v = acc[c][r] + bcol;
      acc[c][r] = v;
      s[r] += v;
      q[r] += v * v;
    }
  }
  #pragma unroll
  for (int m = 1; m < 16; m <<= 1) {
    #pragma unroll
    for (int r = 0; r < 4; ++r) {
      s[r] += __shfl_xor(s[r], m);
      q[r] += __shfl_xor(q[r], m);
    }
  }
  const int g = l >> 4;               // lane group = row block
  if ((l & 15) == 0) {
    #pragma unroll
    for (int r = 0; r < 4; ++r) {
      red[w][g][0][r] = s[r];
      red[w][g][1][r] = q[r];
    }
  }
  __syncthreads();

  float mu[4], rs[4];
  #pragma unroll
  for (int r = 0; r < 4; ++r) {
    float ss = red[0][g][0][r] + red[1][g][0][r] + red[2][g][0][r] + red[3][g][0][r];
    float qq = red[0][g][1][r] + red[1][g][1][r] + red[2][g][1][r] + red[3][g][1][r];
    mu[r] = ss * (1.0f / 256.0f);
    float var = qq * (1.0f / 256.0f) - mu[r] * mu[r];
    rs[r] = rsqrtf(var + 1e-5f);
  }

  const int rowb = row0 + (g << 2);
  #pragma unroll
  for (int c = 0; c < 4; ++c) {
    int col = (w * 4 + c) * 16 + (l & 15);
    float ga = gb[b * 512 + col];
    float be = gb[b * 512 + 256 + col];
    #pragma unroll
    for (int r = 0; r < 4; ++r) {
      float h = (acc[c][r] - mu[r]) * rs[r];
      nnf[(size_t)(rowb + r) * 256 + col] = f2b(fmaxf(h * ga + be, 0.f));
    }
  }
}

// ---------------------------------------------------------------------------
// K3: out = relu(nnf + sum_k ew[k]*nnf[coords[k]])  (f32 out, bf16 table)
// One wave per row. PAIRED gathers: 16B/lane, half-wave per gathered row ->
// each instruction fetches TWO random 512B rows (16 instr for K=32).
// Lane (m,h): m=lane&31 covers cols 8m..8m+7, h=lane>>5 takes k=2t+h.
// Cross-half combine via shfl_xor(32). out stores + coord loads nontemporal
// to preserve nnf L2 residency.
// ---------------------------------------------------------------------------
__global__ __launch_bounds__(256) void k_gather(const u16* __restrict__ nnf,
                                                const float* __restrict__ wts,
                                                const float* __restrict__ prm,
                                                const int* __restrict__ coords,
                                                float* __restrict__ out) {
  int t = blockIdx.x * 256 + threadIdx.x;
  int row  = t >> 6;          // 0..16383
  int lane = t & 63;
  int m = lane & 31;
  int h = lane >> 5;

  int base = row * 32 + m;
  int idx_l  = __builtin_nontemporal_load(coords + base);
  float ew_l = __builtin_nontemporal_load(wts + base) *
               __builtin_nontemporal_load(prm + base);

  const u16* colp = nnf + m * 8;

  u16x8 v[16];
  #pragma unroll
  for (int k = 0; k < 16; ++k) {
    int idx = __shfl(idx_l, 2 * k + h);
    v[k] = *(const u16x8*)(colp + ((size_t)idx << 8));
  }

  float acc[8] = {0.f, 0.f, 0.f, 0.f, 0.f, 0.f, 0.f, 0.f};
  #pragma unroll
  for (int k = 0; k < 16; ++k) {
    float ew = __shfl(ew_l, 2 * k + h);
    #pragma unroll
    for (int e = 0; e < 8; ++e)
      acc[e] += ew * b2f(v[k][e]);
  }
  // combine even-k half (h=0) with odd-k half (h=1)
  #pragma unroll
  for (int e = 0; e < 8; ++e)
    acc[e] += __shfl_xor(acc[e], 32);

  // lane (m,h) writes cols 8m+4h .. 8m+4h+3
  int col = m * 8 + h * 4;
  u16x4 sv = *(const u16x4*)(nnf + ((size_t)row << 8) + col);
  f32x4 o;
  o.x = fmaxf(b2f(sv.x) + acc[h * 4 + 0], 0.f);
  o.y = fmaxf(b2f(sv.y) + acc[h * 4 + 1], 0.f);
  o.z = fmaxf(b2f(sv.z) + acc[h * 4 + 2], 0.f);
  o.w = fmaxf(b2f(sv.w) + acc[h * 4 + 3], 0.f);
  __builtin_nontemporal_store(o, (f32x4*)(out + (size_t)row * 256 + col));
}

// ---------------------------------------------------------------------------
extern "C" void kernel_launch(void* const* d_in, const int* in_sizes, int n_in,
                              void* d_out, int out_size, void* d_ws, size_t ws_size,
                              hipStream_t stream) {
  const float* node = (const float*)d_in[0];
  const float* cond = (const float*)d_in[1];
  const float* Wc   = (const float*)d_in[2];
  const float* bc   = (const float*)d_in[3];
  const float* Wf   = (const float*)d_in[4];
  const float* bf   = (const float*)d_in[5];
  const float* wts  = (const float*)d_in[6];
  const float* prm  = (const float*)d_in[7];
  const int* coords = (const int*)d_in[8];
  float* out = (float*)d_out;

  char* ws = (char*)d_ws;
  float* gb = (float*)ws;                       // 8*512 f32      = 16 KB
  u16* Wp   = (u16*)(ws + 16384);               // 65536 u16      = 128 KB
  u16* nnf  = (u16*)(ws + 16384 + 131072);      // 16384*256 bf16 = 8 MB

  k_prep<<<dim3(48), dim3(256), 0, stream>>>(Wf, Wp, cond, Wc, bc, gb);
  k_film<<<dim3(1024), dim3(256), 0, stream>>>(node, Wp, bf, gb, nnf);
  k_gather<<<dim3(4096), dim3(256), 0, stream>>>(nnf, wts, prm, coords, out);
}

// Round 6
// 55.582 us; speedup vs baseline: 1.4017x; 1.4017x over previous
//
#include <hip/hip_runtime.h>

// Problem: B=8, N=2048, K=32, C=256, COND=512 — ALL FLOAT32 I/O, coords int32.
// Output: f32 [8,2048,256]

typedef unsigned short u16;
typedef unsigned int u32;

typedef __attribute__((ext_vector_type(8))) __bf16 bf16x8;
typedef __attribute__((ext_vector_type(4))) float f32x4;
typedef __attribute__((ext_vector_type(2))) float f32x2;

__device__ __forceinline__ float b2f(u16 u) {
  union { u32 i; float f; } x; x.i = ((u32)u) << 16; return x.f;
}
__device__ __forceinline__ u16 f2b(float f) {
  union { float f; u32 i; } x; x.f = f;
  u32 r = (x.i + 0x7fffu + ((x.i >> 16) & 1u)) >> 16;
  return (u16)r;
}

// ---------------------------------------------------------------------------
// K0: prep.
//  blocks  0..31 : W_film repack to MFMA-B fragment order (bf16)
//  blocks 32..63 : cond GEMM partials, split over k-halves and col-halves
//                  gbp[(kh*8+b)*512 + j] = sum_{i in kh} cond[b][i]*Wc[i][j]
//  blocks 64..95 : ew = weights*params  (524288 f32)
// ---------------------------------------------------------------------------
__global__ __launch_bounds__(256) void k_prep(const float* __restrict__ Wf,
                                              u16* __restrict__ Wp,
                                              const float* __restrict__ cond,
                                              const float* __restrict__ Wc,
                                              float* __restrict__ gbp,
                                              const float* __restrict__ wts,
                                              const float* __restrict__ prm,
                                              float* __restrict__ ew) {
  int blk = blockIdx.x;
  int tid = threadIdx.x;
  if (blk < 32) {
    int i0 = blk * 2048 + tid;
    #pragma unroll
    for (int u = 0; u < 8; ++u) {
      int i = i0 + u * 256;
      int j  = i & 7;
      int l  = (i >> 3) & 63;
      int ks = (i >> 9) & 7;
      int ct = i >> 12;
      int k   = ks * 32 + ((l >> 4) << 3) + j;
      int col = ct * 16 + (l & 15);
      Wp[i] = f2b(Wf[k * 256 + col]);
    }
  } else if (blk < 64) {
    int idx = blk - 32;          // 0..31
    int b  = idx >> 2;           // batch 0..7
    int kh = (idx >> 1) & 1;     // k-half
    int ch = idx & 1;            // col-half
    int j  = ch * 256 + tid;
    __shared__ float cf[256];
    cf[tid] = cond[b * 512 + kh * 256 + tid];
    __syncthreads();
    float a = 0.f;
    #pragma unroll 8
    for (int i = 0; i < 256; ++i)
      a += cf[i] * Wc[(kh * 256 + i) * 512 + j];
    gbp[(kh * 8 + b) * 512 + j] = a;
  } else {
    int i0 = (blk - 64) * 16384 + tid * 4;
    #pragma unroll
    for (int u = 0; u < 16; ++u) {
      int e = i0 + u * 1024;
      f32x4 w = *(const f32x4*)(wts + e);
      f32x4 p = *(const f32x4*)(prm + e);
      f32x4 r = w * p;
      *(f32x4*)(ew + e) = r;
    }
  }
}

// ---------------------------------------------------------------------------
// K1: nnf = bf16( relu(LN(node_feats @ W_film + b_film) * gamma + beta) )
// 512 blocks × 256 thr (4 waves), 32 rows/block (2 row-tiles of 16).
// A staged to LDS bf16 [32][264] via flat fully-coalesced loads.
// Wave w owns col-tiles ct=w*4..w*4+3 for BOTH row-tiles (amortizes Wp reads).
// LN: intra-wave shfl over 16-lane groups, cross-wave via LDS.
// gamma/beta assembled from gbp k-partials + b_cond (+1 for gamma).
// D frag: col = ct*16+(l&15), row = rowtile + (l>>4)*4 + r
// ---------------------------------------------------------------------------
__global__ __launch_bounds__(256) void k_film(const float* __restrict__ A,
                                              const u16* __restrict__ Wp,
                                              const float* __restrict__ bfm,
                                              const float* __restrict__ gbp,
                                              const float* __restrict__ bcond,
                                              u16* __restrict__ nnf) {
  const int tid = threadIdx.x;
  const int l = tid & 63;
  const int w = tid >> 6;
  const int row0 = blockIdx.x * 32;   // 512 blocks
  const int b = row0 >> 11;

  __shared__ u16 As[32 * 264];
  __shared__ float red[4][2][4][2][4];  // [wave][rb][group][s|q][r]

  // Stage: flat coalesced, f32 -> bf16
  #pragma unroll
  for (int u = 0; u < 8; ++u) {
    int f = u * 256 + tid;            // f32x4 index
    int row = f >> 6;
    int col = (f & 63) * 4;
    f32x4 v = *(const f32x4*)(A + (size_t)(row0 + row) * 256 + col);
    u16* dst = As + row * 264 + col;
    dst[0] = f2b(v.x); dst[1] = f2b(v.y); dst[2] = f2b(v.z); dst[3] = f2b(v.w);
  }
  __syncthreads();

  f32x4 acc[2][4];
  #pragma unroll
  for (int rb = 0; rb < 2; ++rb)
    #pragma unroll
    for (int c = 0; c < 4; ++c) {
      acc[rb][c].x = 0.f; acc[rb][c].y = 0.f;
      acc[rb][c].z = 0.f; acc[rb][c].w = 0.f;
    }

  const u16* asrc = As + (l & 15) * 264 + ((l >> 4) << 3);
  const u16* wl = Wp + (size_t)l * 8;

  #pragma unroll
  for (int ks = 0; ks < 8; ++ks) {
    bf16x8 af0 = *(const bf16x8*)(asrc + ks * 32);
    bf16x8 af1 = *(const bf16x8*)(asrc + 16 * 264 + ks * 32);
    #pragma unroll
    for (int c = 0; c < 4; ++c) {
      int ct = w * 4 + c;
      bf16x8 bfr = *(const bf16x8*)(wl + ((size_t)(ct * 8 + ks)) * 512);
      acc[0][c] = __builtin_amdgcn_mfma_f32_16x16x32_bf16(af0, bfr, acc[0][c], 0, 0, 0);
      acc[1][c] = __builtin_amdgcn_mfma_f32_16x16x32_bf16(af1, bfr, acc[1][c], 0, 0, 0);
    }
  }

  const int g = l >> 4;
  #pragma unroll
  for (int rb = 0; rb < 2; ++rb) {
    float s[4] = {0.f, 0.f, 0.f, 0.f};
    float q[4] = {0.f, 0.f, 0.f, 0.f};
    #pragma unroll
    for (int c = 0; c < 4; ++c) {
      float bcol = bfm[(w * 4 + c) * 16 + (l & 15)];
      #pragma unroll
      for (int r = 0; r < 4; ++r) {
        float v = acc[rb][c][r] + bcol;
        acc[rb][c][r] = v;
        s[r] += v;
        q[r] += v * v;
      }
    }
    #pragma unroll
    for (int m = 1; m < 16; m <<= 1) {
      #pragma unroll
      for (int r = 0; r < 4; ++r) {
        s[r] += __shfl_xor(s[r], m);
        q[r] += __shfl_xor(q[r], m);
      }
    }
    if ((l & 15) == 0) {
      #pragma unroll
      for (int r = 0; r < 4; ++r) {
        red[w][rb][g][0][r] = s[r];
        red[w][rb][g][1][r] = q[r];
      }
    }
  }
  __syncthreads();

  #pragma unroll
  for (int rb = 0; rb < 2; ++rb) {
    float mu[4], rs[4];
    #pragma unroll
    for (int r = 0; r < 4; ++r) {
      float ss = red[0][rb][g][0][r] + red[1][rb][g][0][r] +
                 red[2][rb][g][0][r] + red[3][rb][g][0][r];
      float qq = red[0][rb][g][1][r] + red[1][rb][g][1][r] +
                 red[2][rb][g][1][r] + red[3][rb][g][1][r];
      mu[r] = ss * (1.0f / 256.0f);
      float var = qq * (1.0f / 256.0f) - mu[r] * mu[r];
      rs[r] = rsqrtf(var + 1e-5f);
    }
    const int rowb = row0 + rb * 16 + (g << 2);
    #pragma unroll
    for (int c = 0; c < 4; ++c) {
      int col = (w * 4 + c) * 16 + (l & 15);
      float ga = gbp[b * 512 + col] + gbp[(8 + b) * 512 + col] + bcond[col] + 1.0f;
      float be = gbp[b * 512 + 256 + col] + gbp[(8 + b) * 512 + 256 + col] + bcond[256 + col];
      #pragma unroll
      for (int r = 0; r < 4; ++r) {
        float h = (acc[rb][c][r] - mu[r]) * rs[r];
        nnf[(size_t)(rowb + r) * 256 + col] = f2b(fmaxf(h * ga + be, 0.f));
      }
    }
  }
}

// ---------------------------------------------------------------------------
// K2: out = relu(nnf + sum_k ew[k]*nnf[coords[k]])  — COLUMN-QUARTER SLICED.
// Quarter q's nnf slice = 16384 rows × 64 cols bf16 = 2 MB -> L2-resident.
// Grid 8192: q = blk>>11 (temporal phasing via dispatch order — perf only).
// Block = 4 waves = 8 rows. Half-wave h owns one row; lane m=lane&31 owns
// cols q*64 + 2m (u32 = 2 bf16). 32 gathers/row, each a single 128B line.
// coords/ew loads + out stores nontemporal (protect the L2 slice).
// ---------------------------------------------------------------------------
__global__ __launch_bounds__(256) void k_gather(const u16* __restrict__ nnf,
                                                const float* __restrict__ ew,
                                                const int* __restrict__ coords,
                                                float* __restrict__ out) {
  int q  = blockIdx.x >> 11;          // 0..3
  int bi = blockIdx.x & 2047;
  int wv = threadIdx.x >> 6;
  int lane = threadIdx.x & 63;
  int h = lane >> 5;
  int m = lane & 31;
  int row = bi * 8 + wv * 2 + h;      // 0..16383

  int e = row * 32 + m;
  int idx_l  = __builtin_nontemporal_load(coords + e);
  float ew_l = __builtin_nontemporal_load(ew + e);

  const u16* colp = nnf + q * 64 + m * 2;

  u32 v[32];
  #pragma unroll
  for (int k = 0; k < 32; ++k) {
    int idx = __shfl(idx_l, k, 32);
    v[k] = *(const u32*)(colp + ((size_t)idx << 8));
  }

  float a0 = 0.f, a1 = 0.f;
  #pragma unroll
  for (int k = 0; k < 32; ++k) {
    float w = __shfl(ew_l, k, 32);
    a0 += w * b2f((u16)(v[k] & 0xffff));
    a1 += w * b2f((u16)(v[k] >> 16));
  }

  u32 sv = *(const u32*)(colp + ((size_t)row << 8));
  f32x2 o;
  o.x = fmaxf(b2f((u16)(sv & 0xffff)) + a0, 0.f);
  o.y = fmaxf(b2f((u16)(sv >> 16)) + a1, 0.f);
  __builtin_nontemporal_store(o, (f32x2*)(out + (size_t)row * 256 + q * 64 + m * 2));
}

// ---------------------------------------------------------------------------
extern "C" void kernel_launch(void* const* d_in, const int* in_sizes, int n_in,
                              void* d_out, int out_size, void* d_ws, size_t ws_size,
                              hipStream_t stream) {
  const float* node = (const float*)d_in[0];
  const float* cond = (const float*)d_in[1];
  const float* Wc   = (const float*)d_in[2];
  const float* bc   = (const float*)d_in[3];
  const float* Wf   = (const float*)d_in[4];
  const float* bf   = (const float*)d_in[5];
  const float* wts  = (const float*)d_in[6];
  const float* prm  = (const float*)d_in[7];
  const int* coords = (const int*)d_in[8];
  float* out = (float*)d_out;

  char* ws = (char*)d_ws;
  float* gbp = (float*)ws;                        // 2*8*512 f32 = 32 KB
  u16* Wp    = (u16*)(ws + 32768);                // 128 KB
  float* ew  = (float*)(ws + 32768 + 131072);     // 2 MB
  u16* nnf   = (u16*)(ws + 32768 + 131072 + 2097152);  // 8 MB

  k_prep<<<dim3(96), dim3(256), 0, stream>>>(Wf, Wp, cond, Wc, gbp, wts, prm, ew);
  k_film<<<dim3(512), dim3(256), 0, stream>>>(node, Wp, bf, gbp, bc, nnf);
  k_gather<<<dim3(8192), dim3(256), 0, stream>>>(nnf, ew, coords, out);
}